// Round 6
// baseline (812.579 us; speedup 1.0000x reference)
//
#include <hip/hip_runtime.h>
#include <hip/hip_bf16.h>

typedef __hip_bfloat16 bf16;
typedef __attribute__((ext_vector_type(8))) short short8;
typedef __attribute__((ext_vector_type(4))) float float4v;

// ---- problem constants ----
#define N1 120000
#define N2 20000
#define N3 4000
#define E0 1800000
#define E1 200000
#define E2 20000
#define D_IN 128
#define D_HID 256
#define D_OUT 47

// bucket width = 512 dsts (shift 9). buckets per layer:
#define NB0 235
#define NB1 40
#define NB2 8
#define BCAP 32

__device__ __forceinline__ void stv(float* p, float v) { *p = v; }
__device__ __forceinline__ void stv(bf16* p, float v) { *p = __float2bfloat16(v); }

__device__ __forceinline__ unsigned short f2bu(float v) {
    union { bf16 h; unsigned short u; } c;
    c.h = __float2bfloat16(v);
    return c.u;
}
__device__ __forceinline__ short f2bs(float v) { return (short)f2bu(v); }
__device__ __forceinline__ float bu2f(unsigned short u) { return __uint_as_float(((unsigned)u) << 16); }

__device__ __forceinline__ short8 load8(const bf16* p) {
    union { uint4 u; short8 s; } r;
    r.u = *(const uint4*)p;
    return r.s;
}
__device__ __forceinline__ short8 load8(const float* p) {
    float4 a = *(const float4*)p;
    float4 b = *(const float4*)(p + 4);
    short8 s;
    s[0] = f2bs(a.x); s[1] = f2bs(a.y); s[2] = f2bs(a.z); s[3] = f2bs(a.w);
    s[4] = f2bs(b.x); s[5] = f2bs(b.y); s[6] = f2bs(b.z); s[7] = f2bs(b.w);
    return s;
}

// ================= x -> bf16 conversion =================
__global__ __launch_bounds__(256) void convert_x(const float* __restrict__ x,
                                                 bf16* __restrict__ xb, int n8) {
    int i = blockIdx.x * blockDim.x + threadIdx.x;
    if (i >= n8) return;
    const float* p = x + (size_t)i * 8;
    float4 a = *(const float4*)p;
    float4 b = *(const float4*)(p + 4);
    union { uint4 u; short s[8]; } o;
    o.s[0] = f2bs(a.x); o.s[1] = f2bs(a.y); o.s[2] = f2bs(a.z); o.s[3] = f2bs(a.w);
    o.s[4] = f2bs(b.x); o.s[5] = f2bs(b.y); o.s[6] = f2bs(b.z); o.s[7] = f2bs(b.w);
    *(uint4*)(xb + (size_t)i * 8) = o.u;
}

// ================= batched weight transpose+convert =================
__global__ void wt_batch(const float* W0s, const float* W0n, const float* W1s,
                         const float* W1n, const float* W2s, const float* W2n,
                         bf16* T0s, bf16* T0n, bf16* T1s, bf16* T1n, bf16* T2s, bf16* T2n) {
    int i = blockIdx.x * blockDim.x + threadIdx.x;
    const float* W; bf16* T; int K, N, j;
    if      (i <  32768) { W = W0s; T = T0s; K = 128; N = 256; j = i; }
    else if (i <  65536) { W = W0n; T = T0n; K = 128; N = 256; j = i - 32768; }
    else if (i < 131072) { W = W1s; T = T1s; K = 256; N = 256; j = i - 65536; }
    else if (i < 196608) { W = W1n; T = T1n; K = 256; N = 256; j = i - 131072; }
    else if (i < 208896) { W = W2s; T = T2s; K = 256; N = 47;  j = i - 196608; }
    else if (i < 221184) { W = W2n; T = T2n; K = 256; N = 47;  j = i - 208896; }
    else return;
    int n = j / K, k = j - n * K;
    float v = (n < N) ? W[(size_t)k * N + n] : 0.f;
    T[j] = __float2bfloat16(v);
}

// ================= phase 1: bucket histogram (LDS-staged) =================
// 4096 edges per WG. blocks: L0 [0,440), L1 [440,489), L2 [489,494)
__global__ __launch_bounds__(256) void bucket_hist(
    const int* __restrict__ d0, const int* __restrict__ d1, const int* __restrict__ d2,
    int* __restrict__ bc) {
    __shared__ int h[NB0];
    int b = blockIdx.x, t = threadIdx.x;
    const int* dst; int* bcl; int e0, e1, nb;
    if (b < 440)      { dst = d0; bcl = bc;       nb = NB0; e0 = b * 4096;         e1 = min(e0 + 4096, E0); }
    else if (b < 489) { dst = d1; bcl = bc + 256; nb = NB1; e0 = (b - 440) * 4096; e1 = min(e0 + 4096, E1); }
    else              { dst = d2; bcl = bc + 512; nb = NB2; e0 = (b - 489) * 4096; e1 = min(e0 + 4096, E2); }
    for (int i = t; i < nb; i += 256) h[i] = 0;
    __syncthreads();
    for (int e = e0 + t; e < e1; e += 256) atomicAdd(&h[dst[e] >> 9], 1);
    __syncthreads();
    for (int i = t; i < nb; i += 256) { int v = h[i]; if (v) atomicAdd(&bcl[i], v); }
}

// ================= phase 2: bucket exclusive scan, cursor init, rp[N]=E =================
__global__ __launch_bounds__(256) void bucket_scan(
    const int* __restrict__ bc, int* __restrict__ bb, int* __restrict__ bu,
    int* __restrict__ rp0, int* __restrict__ rp1, int* __restrict__ rp2) {
    __shared__ int sd[256];
    int l = blockIdx.x, t = threadIdx.x;
    int nb = (l == 0) ? NB0 : (l == 1 ? NB1 : NB2);
    const int* bcl = bc + l * 256;
    int* bbl = bb + l * 256;
    int* bul = bu + l * 256;
    int v = (t < nb) ? bcl[t] : 0;
    sd[t] = v;
    __syncthreads();
    for (int off = 1; off < 256; off <<= 1) {
        int x = (t >= off) ? sd[t - off] : 0;
        __syncthreads();
        sd[t] += x;
        __syncthreads();
    }
    int ex = sd[t] - v;
    if (t < nb) { bbl[t] = ex; bul[t] = ex; }
    if (t == 0) {
        if (l == 0) rp0[N1] = E0;
        else if (l == 1) rp1[N2] = E1;
        else rp2[N3] = E2;
    }
}

// ================= phase 3: LDS-binned edge partition =================
// packed entry = (src << 9) | (dst & 511). blocks: L0 [0,48), L1 [48,60), L2 [60,62)
__global__ __launch_bounds__(256) void bin_pass(
    const int* __restrict__ s0, const int* __restrict__ d0,
    const int* __restrict__ s1, const int* __restrict__ d1,
    const int* __restrict__ s2, const int* __restrict__ d2,
    int* __restrict__ bu, int* __restrict__ eb0, int* __restrict__ eb1,
    int* __restrict__ eb2) {
    __shared__ int cnt[NB0];
    __shared__ int data[NB0 * BCAP];  // 30,080 B
    int b = blockIdx.x, t = threadIdx.x;
    const int *src, *dst; int *cur, *eb; int nb, e0, e1;
    if (b < 48)      { src = s0; dst = d0; cur = bu;       eb = eb0; nb = NB0; e0 = b * 37888;        e1 = min(e0 + 37888, E0); }
    else if (b < 60) { src = s1; dst = d1; cur = bu + 256; eb = eb1; nb = NB1; e0 = (b - 48) * 17408; e1 = min(e0 + 17408, E1); }
    else             { src = s2; dst = d2; cur = bu + 512; eb = eb2; nb = NB2; e0 = (b - 60) * 10240; e1 = min(e0 + 10240, E2); }
    for (int i = t; i < nb; i += 256) cnt[i] = 0;
    __syncthreads();
    for (int rb = e0; rb < e1; rb += 1024) {
        #pragma unroll
        for (int j = 0; j < 4; j++) {
            int e = rb + j * 256 + t;
            if (e < e1) {
                int d = dst[e];
                int gb = d >> 9;
                int pk = (src[e] << 9) | (d & 511);
                int pos = atomicAdd(&cnt[gb], 1);
                if (pos < BCAP) data[gb * BCAP + pos] = pk;
                else { int p = atomicAdd(&cur[gb], 1); eb[p] = pk; }  // rare overflow
            }
        }
        __syncthreads();
        if (t < nb) {
            int c = cnt[t];
            if (c >= BCAP) {  // flush a full bin: 128B contiguous chunk
                int p = atomicAdd(&cur[t], BCAP);
                #pragma unroll
                for (int j = 0; j < BCAP; j++) eb[p + j] = data[t * BCAP + j];
                cnt[t] = 0;
            }
        }
        __syncthreads();
    }
    if (t < nb) {  // final partial flush
        int c = min(cnt[t], BCAP);
        if (c > 0) {
            int p = atomicAdd(&cur[t], c);
            for (int j = 0; j < c; j++) eb[p + j] = data[t * BCAP + j];
        }
    }
}

// ================= phase 4: per-bucket local CSR (rp + col) =================
// blocks: L0 [0,235), L1 [235,275), L2 [275,283)
__global__ __launch_bounds__(256) void local_csr(
    const int* __restrict__ bb, const int* __restrict__ bc,
    const int* __restrict__ eb0, const int* __restrict__ eb1, const int* __restrict__ eb2,
    int* __restrict__ rp0, int* __restrict__ rp1, int* __restrict__ rp2,
    int* __restrict__ col0, int* __restrict__ col1, int* __restrict__ col2) {
    __shared__ int lcnt[512];
    __shared__ int lrp[512];
    __shared__ int sscan[256];
    int b = blockIdx.x, t = threadIdx.x;
    const int *eb; int *rp, *col; int bkt, Nl, loff;
    if (b < 235)      { bkt = b;       eb = eb0; rp = rp0; col = col0; Nl = N1; loff = 0; }
    else if (b < 275) { bkt = b - 235; eb = eb1; rp = rp1; col = col1; Nl = N2; loff = 256; }
    else              { bkt = b - 275; eb = eb2; rp = rp2; col = col2; Nl = N3; loff = 512; }
    int base = bb[loff + bkt];
    int cb   = bc[loff + bkt];
    int dbase = bkt << 9;
    int nloc = min(512, Nl - dbase);
    lcnt[t] = 0; lcnt[t + 256] = 0;
    __syncthreads();
    for (int i = t; i < cb; i += 256) atomicAdd(&lcnt[eb[base + i] & 511], 1);
    __syncthreads();
    // exclusive scan of 512 counters
    int a0 = lcnt[2 * t], a1 = lcnt[2 * t + 1];
    sscan[t] = a0 + a1;
    __syncthreads();
    for (int off = 1; off < 256; off <<= 1) {
        int x = (t >= off) ? sscan[t - off] : 0;
        __syncthreads();
        sscan[t] += x;
        __syncthreads();
    }
    int ex = sscan[t] - (a0 + a1);
    lrp[2 * t] = ex;
    lrp[2 * t + 1] = ex + a0;
    __syncthreads();
    for (int i = t; i < nloc; i += 256) rp[dbase + i] = base + lrp[i];
    for (int i = t; i < cb; i += 256) {
        int pk = eb[base + i];
        int ld = pk & 511;
        int ofs = atomicSub(&lcnt[ld], 1) - 1;
        col[base + lrp[ld] + ofs] = pk >> 9;
    }
}

// ================= gather-mean (one wave per dst node), bf16 out =================
template <int DIN, typename T>
__global__ __launch_bounds__(256) void gather_mean(const T* __restrict__ h,
        const int* __restrict__ rp, const int* __restrict__ col,
        int n_dst, bf16* __restrict__ agg) {
    int gw = (blockIdx.x * blockDim.x + threadIdx.x) >> 6;
    int lane = threadIdx.x & 63;
    if (gw >= n_dst) return;
    int beg = rp[gw], end = rp[gw + 1];
    constexpr int VP = DIN / 64;
    float s[VP] = {};

    auto accum = [&](int srcn) {
        const T* hp = h + (size_t)srcn * DIN + lane * VP;
        if constexpr (sizeof(T) == 4) {  // float, VP==2
            float2 v = *(const float2*)hp;
            s[0] += v.x; s[1] += v.y;
        } else if constexpr (VP == 2) {  // bf16 x2
            union { unsigned u; unsigned short us[2]; } r;
            r.u = *(const unsigned*)hp;
            s[0] += bu2f(r.us[0]); s[1] += bu2f(r.us[1]);
        } else {  // bf16 x4
            union { uint2 u; unsigned short us[4]; } r;
            r.u = *(const uint2*)hp;
            #pragma unroll
            for (int j = 0; j < 4; j++) s[j] += bu2f(r.us[j]);
        }
    };

    int e = beg;
    for (; e + 3 < end; e += 4) {
        int a0 = col[e], a1 = col[e + 1], a2 = col[e + 2], a3 = col[e + 3];
        accum(a0); accum(a1); accum(a2); accum(a3);
    }
    for (; e < end; ++e) accum(col[e]);

    float inv = 1.f / fmaxf((float)(end - beg), 1.f);
    #pragma unroll
    for (int j = 0; j < VP; j++) s[j] *= inv;

    bf16* ap = agg + (size_t)gw * DIN + lane * VP;
    if constexpr (VP == 2) {
        ushort2 o; o.x = f2bu(s[0]); o.y = f2bu(s[1]);
        *(ushort2*)ap = o;
    } else {
        ushort4 o; o.x = f2bu(s[0]); o.y = f2bu(s[1]); o.z = f2bu(s[2]); o.w = f2bu(s[3]);
        *(ushort4*)ap = o;
    }
}

// ================= fused MFMA SAGE GEMM =================
// Block tile 128(m) x 128(n), 4 waves of 64x64, 16x16x32 MFMA, BK=32.
template <typename TA, typename TC, bool RELU>
__global__ __launch_bounds__(256) void gemm_mfma(
    const TA* __restrict__ A, const bf16* __restrict__ Mn,
    const bf16* __restrict__ Wst, const bf16* __restrict__ Wnt,
    const float* __restrict__ bias, TC* __restrict__ C,
    int M, int Nstore, int Npad, int K) {
    __shared__ short As[128][48];
    __shared__ short Bs[128][48];

    int tid = threadIdx.x;
    int m0 = blockIdx.x * 128;
    int n0 = blockIdx.y * 128;
    int lane = tid & 63, wid = tid >> 6;
    int wm = (wid & 1) * 64, wn = (wid >> 1) * 64;
    int l15 = lane & 15, quad = lane >> 4;

    float4v acc[4][4] = {};

    int nsteps = (2 * K) >> 5;
    int r = tid >> 2, c = (tid & 3) << 3;
    for (int s = 0; s < nsteps; ++s) {
        int ks = s << 5;
        bool self = ks < K;
        int ko = self ? ks : ks - K;
        #pragma unroll
        for (int it = 0; it < 2; ++it) {
            int rr = r + it * 64;
            {
                int gm = m0 + rr;
                short8 v = (short8)0;
                if (gm < M) {
                    if (self) v = load8(A  + (size_t)gm * K + ko + c);
                    else      v = load8(Mn + (size_t)gm * K + ko + c);
                }
                *(short8*)&As[rr][c] = v;
            }
            {
                int gn = n0 + rr;
                short8 w = (short8)0;
                if (gn < Npad) {
                    const bf16* Wp = self ? Wst : Wnt;
                    w = load8(Wp + (size_t)gn * K + ko + c);
                }
                *(short8*)&Bs[rr][c] = w;
            }
        }
        __syncthreads();
        short8 af[4], bfr[4];
        #pragma unroll
        for (int i = 0; i < 4; ++i)
            af[i] = *(const short8*)&As[wm + i * 16 + l15][quad * 8];
        #pragma unroll
        for (int j = 0; j < 4; ++j)
            bfr[j] = *(const short8*)&Bs[wn + j * 16 + l15][quad * 8];
        #pragma unroll
        for (int i = 0; i < 4; ++i)
            #pragma unroll
            for (int j = 0; j < 4; ++j)
                acc[i][j] = __builtin_amdgcn_mfma_f32_16x16x32_bf16(af[i], bfr[j], acc[i][j], 0, 0, 0);
        __syncthreads();
    }

    #pragma unroll
    for (int i = 0; i < 4; ++i) {
        #pragma unroll
        for (int j = 0; j < 4; ++j) {
            int gn = n0 + wn + j * 16 + l15;
            if (gn >= Nstore) continue;
            float bv = bias[gn];
            #pragma unroll
            for (int rr = 0; rr < 4; ++rr) {
                int gm = m0 + wm + i * 16 + quad * 4 + rr;
                if (gm >= M) continue;
                float v = acc[i][j][rr] + bv;
                if (RELU) v = fmaxf(v, 0.f);
                stv(&C[(size_t)gm * Nstore + gn], v);
            }
        }
    }
}

// ================= launch =================
extern "C" void kernel_launch(void* const* d_in, const int* in_sizes, int n_in,
                              void* d_out, int out_size, void* d_ws, size_t ws_size,
                              hipStream_t stream) {
    const float* x    = (const float*)d_in[0];
    const int*  src0 = (const int*)d_in[1];
    const int*  dst0 = (const int*)d_in[2];
    const int*  src1 = (const int*)d_in[3];
    const int*  dst1 = (const int*)d_in[4];
    const int*  src2 = (const int*)d_in[5];
    const int*  dst2 = (const int*)d_in[6];
    const float* Ws0 = (const float*)d_in[7];
    const float* Wn0 = (const float*)d_in[8];
    const float* b0  = (const float*)d_in[9];
    const float* Ws1 = (const float*)d_in[10];
    const float* Wn1 = (const float*)d_in[11];
    const float* b1  = (const float*)d_in[12];
    const float* Ws2 = (const float*)d_in[13];
    const float* Wn2 = (const float*)d_in[14];
    const float* b2  = (const float*)d_in[15];
    float* out = (float*)d_out;

    char* W = (char*)d_ws;
    // ---- persistent region ----
    int* rp0   = (int*)(W + 0);          // 480,004
    int* rp1   = (int*)(W + 480004);     //  80,004
    int* rp2   = (int*)(W + 560008);     //  16,004  (end 576,012 -> pad 576,016)
    int* col0  = (int*)(W + 576016);     // 7,200,000
    int* col1  = (int*)(W + 7776016);    //   800,000
    int* col2  = (int*)(W + 8576016);    //    80,000
    int* eb0   = (int*)(W + 8656016);    // 7,200,000
    int* eb1   = (int*)(W + 15856016);   //   800,000
    int* eb2   = (int*)(W + 16656016);   //    80,000
    int* bcnt  = (int*)(W + 16736016);   //     3,072 (3 x 256 ints)  [memset]
    int* bbase = (int*)(W + 16739088);   //     3,072
    int* bcur  = (int*)(W + 16742160);   //     3,072 (end 16,745,232)
    bf16* Wst0 = (bf16*)(W + 16745232);  //    65,536
    bf16* Wnt0 = (bf16*)(W + 16810768);  //    65,536
    bf16* Wst1 = (bf16*)(W + 16876304);  //   131,072
    bf16* Wnt1 = (bf16*)(W + 17007376);  //   131,072
    bf16* Wst2 = (bf16*)(W + 17138448);  //    24,576
    bf16* Wnt2 = (bf16*)(W + 17163024);  //    24,576 (end 17,187,600; pad)

    const size_t BASE = 17187840;
    const bool use_xb = ws_size >= (size_t)(BASE + 102400000 + 30720000 + 61440000 + 1024);
    bf16* xb = (bf16*)(W + BASE);                      // 102,400,000 (use_xb only)
    size_t agg0_off = BASE + (use_xb ? 102400000 : 0);
    bf16* agg0 = (bf16*)(W + agg0_off);                // 30,720,000
    bf16* h1   = (bf16*)(W + agg0_off + 30720000);     // 61,440,000
    bf16* agg1 = (bf16*)(W + BASE);                    // 10,240,000 (xb/agg0 dead)
    bf16* h2   = (bf16*)(W + BASE + 10240000);         // 10,240,000
    bf16* agg2 = (bf16*)(W + BASE + 20480000);         //  2,048,000

    // ---- phase A: conversions + bucketed CSR build ----
    hipMemsetAsync(bcnt, 0, 3072, stream);
    if (use_xb) {
        int n8 = 400000 * D_IN / 8;
        convert_x<<<(n8 + 255) / 256, 256, 0, stream>>>(x, xb, n8);
    }
    wt_batch<<<(221184 + 255) / 256, 256, 0, stream>>>(Ws0, Wn0, Ws1, Wn1, Ws2, Wn2,
                                                       Wst0, Wnt0, Wst1, Wnt1, Wst2, Wnt2);
    bucket_hist<<<494, 256, 0, stream>>>(dst0, dst1, dst2, bcnt);
    bucket_scan<<<3, 256, 0, stream>>>(bcnt, bbase, bcur, rp0, rp1, rp2);
    bin_pass<<<62, 256, 0, stream>>>(src0, dst0, src1, dst1, src2, dst2,
                                     bcur, eb0, eb1, eb2);
    local_csr<<<283, 256, 0, stream>>>(bbase, bcnt, eb0, eb1, eb2,
                                       rp0, rp1, rp2, col0, col1, col2);

    // ---- layer 0: 400000 -> 120000, K=128, relu ----
    if (use_xb) {
        gather_mean<D_IN, bf16><<<(N1 + 3) / 4, 256, 0, stream>>>(xb, rp0, col0, N1, agg0);
        dim3 grid((N1 + 127) / 128, 2);
        gemm_mfma<bf16, bf16, true><<<grid, 256, 0, stream>>>(xb, agg0, Wst0, Wnt0, b0, h1, N1, 256, 256, 128);
    } else {
        gather_mean<D_IN, float><<<(N1 + 3) / 4, 256, 0, stream>>>(x, rp0, col0, N1, agg0);
        dim3 grid((N1 + 127) / 128, 2);
        gemm_mfma<float, bf16, true><<<grid, 256, 0, stream>>>(x, agg0, Wst0, Wnt0, b0, h1, N1, 256, 256, 128);
    }

    // ---- layer 1: 120000 -> 20000, K=256, relu ----
    gather_mean<D_HID, bf16><<<(N2 + 3) / 4, 256, 0, stream>>>(h1, rp1, col1, N2, agg1);
    {
        dim3 grid((N2 + 127) / 128, 2);
        gemm_mfma<bf16, bf16, true><<<grid, 256, 0, stream>>>(h1, agg1, Wst1, Wnt1, b1, h2, N2, 256, 256, 256);
    }

    // ---- layer 2: 20000 -> 4000, K=256, no relu ----
    gather_mean<D_HID, bf16><<<(N3 + 3) / 4, 256, 0, stream>>>(h2, rp2, col2, N3, agg2);
    {
        dim3 grid((N3 + 127) / 128, 1);
        gemm_mfma<bf16, float, false><<<grid, 256, 0, stream>>>(h2, agg2, Wst2, Wnt2, b2, out, N3, 47, 48, 256);
    }
}